// Round 6
// baseline (9281.511 us; speedup 1.0000x reference)
//
#include <hip/hip_runtime.h>
#include <cstddef>

#define B_  4
#define N_  4096
#define M_  2048
#define K_  32      // NSAMPLE

typedef short bf16x8 __attribute__((ext_vector_type(8)));
typedef float f32x4  __attribute__((ext_vector_type(4)));

// IEEE mul/add without fma contraction: FPS argmax and ball-query d2<r^2 are
// DISCRETE selectors. This exact form PASSED rounds 2-3 (absmax 9.8e-4).
__device__ __forceinline__ float sq3_rn(float dx, float dy, float dz) {
    return __fadd_rn(__fadd_rn(__fmul_rn(dx, dx), __fmul_rn(dy, dy)), __fmul_rn(dz, dz));
}

// float -> bf16 (RNE) and back, bit-level (no API dependence)
__device__ __forceinline__ unsigned short f2bf(float f) {
    unsigned u = __float_as_uint(f);
    return (unsigned short)((u + 0x7FFFu + ((u >> 16) & 1u)) >> 16);
}
__device__ __forceinline__ float bf2f(unsigned short h) {
    return __uint_as_float(((unsigned)h) << 16);
}

// ---------------------------------------------------------------------------
// FPS: one block per (b,s), 512 threads, 8 pts/thread in registers.
// Per iter: pack (dist_bits<<32)|~idx -> u64 max = argmax w/ first-index ties;
// 6-step shfl_xor butterfly; ONE barrier (parity-buffered cross-wave slots);
// NO global stores in the loop (winners recorded in regs, written at end).
// ---------------------------------------------------------------------------
__global__ __launch_bounds__(512) void fps_kernel(
    const float* __restrict__ xyzs,   // [B,8,4096,3]
    float* __restrict__ out_xyz)      // [B,8,2048,3]
{
    const int blk = blockIdx.x;
    const int tid = threadIdx.x;
    const float* fr = xyzs + (size_t)blk * (N_ * 3);
    float* ox = out_xyz + (size_t)blk * (M_ * 3);

    __shared__ float sx[N_], sy[N_], sz[N_];
    __shared__ unsigned long long sred[2][8];

    float px[8], py[8], pz[8], dist[8];
    unsigned ids[8];
#pragma unroll
    for (int u = 0; u < 8; ++u) {
        const int p = u * 512 + tid;
        const float x = fr[p*3+0], y = fr[p*3+1], z = fr[p*3+2];
        px[u] = x; py[u] = y; pz[u] = z; dist[u] = 1e10f;
        ids[u] = ~(unsigned)p;
        sx[p] = x; sy[p] = y; sz[p] = z;
    }
    __syncthreads();

    const int lane = tid & 63, wave = tid >> 6;
    int last = 0;
    int widx[4];
#pragma unroll
    for (int s = 0; s < 4; ++s) {
        for (int ii = 0; ii < 512; ++ii) {
            if (ii == tid) widx[s] = last;   // output of iter s*512+ii is pre-update last
            const float lx = sx[last], ly = sy[last], lz = sz[last];

            unsigned long long best = 0ull;
#pragma unroll
            for (int u = 0; u < 8; ++u) {
                const float d = sq3_rn(px[u]-lx, py[u]-ly, pz[u]-lz);
                const float nd = fminf(dist[u], d);
                dist[u] = nd;
                const unsigned long long pk =
                    ((unsigned long long)__float_as_uint(nd) << 32) | ids[u];
                best = pk > best ? pk : best;
            }
#pragma unroll
            for (int off = 32; off; off >>= 1) {
                const unsigned long long o = __shfl_xor(best, off);
                best = o > best ? o : best;
            }
            if (lane == 0) sred[ii & 1][wave] = best;
            __syncthreads();
            const unsigned long long* sr = sred[ii & 1];
            unsigned long long b0 = sr[0] > sr[1] ? sr[0] : sr[1];
            unsigned long long b1 = sr[2] > sr[3] ? sr[2] : sr[3];
            unsigned long long b2 = sr[4] > sr[5] ? sr[4] : sr[5];
            unsigned long long b3 = sr[6] > sr[7] ? sr[6] : sr[7];
            b0 = b0 > b1 ? b0 : b1;
            b2 = b2 > b3 ? b2 : b3;
            b0 = b0 > b2 ? b0 : b2;
            last = (int)((~(unsigned)b0) & (N_ - 1));
        }
    }
#pragma unroll
    for (int s = 0; s < 4; ++s) {
        const int it = s * 512 + tid;
        const int w = widx[s];
        ox[it*3+0] = sx[w]; ox[it*3+1] = sy[w]; ox[it*3+2] = sz[w];
    }
}

// ---------------------------------------------------------------------------
// Fused per-wave pipeline: wave <-> anchor, NO barriers in the j-loop.
//   BQ      : wave scans frame -> sbidx[wa][32] (same-wave LDS readback)
//   phase A : gather + layer1 computed DIRECTLY in MFMA B-frag lane layout
//             (lane l: q = nt*16+(l&15), k = ks*32+(l>>4)*8+j), hi/lo bf16
//             split in registers -- h1 never touches LDS
//   phase B : 8mt x 2nt tiles of mfma_f32_16x16x32_bf16, A = Ws1 hi/lo from
//             XOR-swizzled LDS; 3-product split (hh+hl+lh); shfl_xor maxpool
//   phase C : lane owns 4 oc rows of Wt[j] (L2-resident), dot with hmax
// Ws1 frag layout check: A row=l&15, k=(l>>4)*8+i; B col=l&15, k=(l>>4)*8+i;
// D row=(l>>4)*4+r, col=l&15  (CDNA 16x16x32 documented mapping).
// ---------------------------------------------------------------------------
__global__ __launch_bounds__(256, 3) void mlp_kernel(
    const float* __restrict__ xyzs,      // [B,8,4096,3]
    const float* __restrict__ feats,     // [B,8,3,4096]
    const float* __restrict__ Ws0,       // [64,6]
    const float* __restrict__ Ws1,       // [128,64]
    const float* __restrict__ Wt,        // [3,256,128]
    const float* __restrict__ anchors,   // [B,8,2048,3]
    float* __restrict__ out_feat)        // [B,8,256,2048]
{
    const int blk = blockIdx.x;
    const int mb  = blk & 511;
    const int bt  = blk >> 9;
    const int b = bt >> 3, t = bt & 7;
    const int tid = threadIdx.x;
    const int lane = tid & 63, wa = tid >> 6;
    const int lm = lane & 15, lg = lane >> 4;

    // ws1s[part][idx]: idx(oc,k) = oc*64 + (((k>>3)^(oc&7))<<3) + (k&7)
    // -> A-frag b128 reads spread evenly over all 32 banks (no excess conflict)
    __shared__ unsigned short ws1s[2][128 * 64];   // 32 KB
    __shared__ float w0s[64][8];                   // 2 KB (cols 6,7 unused)
    __shared__ float hmaxs[4][128];                // 2 KB
    __shared__ float ancs[4][3];
    __shared__ unsigned short sbidx[4][32];
    float* stg = (float*)ws1s;                     // end-of-kernel overlay (6 KB)

    // ---- one-time staging ----
    for (int i = tid; i < 384; i += 256) w0s[i / 6][i % 6] = Ws0[i];
    {
        const float4* wp4 = (const float4*)Ws1;    // 2048 float4
#pragma unroll
        for (int u = 0; u < 8; ++u) {
            const int f4 = u * 256 + tid;
            const float4 v = wp4[f4];
            const int oc = f4 >> 4;
            const int k0 = (f4 & 15) * 4;
            const float vv[4] = {v.x, v.y, v.z, v.w};
#pragma unroll
            for (int c = 0; c < 4; ++c) {
                const int k = k0 + c;
                const int idx = oc * 64 + (((k >> 3) ^ (oc & 7)) << 3) + (k & 7);
                const unsigned short hi = f2bf(vv[c]);
                const unsigned short lo = f2bf(vv[c] - bf2f(hi));
                ws1s[0][idx] = hi;
                ws1s[1][idx] = lo;
            }
        }
    }
    if (tid < 12) ancs[tid / 3][tid % 3] =
        anchors[((size_t)bt * M_ + mb * 4 + tid / 3) * 3 + tid % 3];
    __syncthreads();

    const float ax = ancs[wa][0], ay = ancs[wa][1], az = ancs[wa][2];
    float st0 = 0.f, st1 = 0.f, st2 = 0.f, st3 = 0.f;   // oc = lane*4 + r

    for (int j = 0; j < 3; ++j) {
        int fi = t + j - 1; fi = fi < 0 ? 0 : (fi > 7 ? 7 : fi);
        const float* fr = xyzs + (size_t)(b * 8 + fi) * (N_ * 3);

        // ---- ball query (per wave; same-wave LDS readback, no barrier) ----
        {
            int cnt = 0, first = 0;
            for (int c = 0; c < 64; ++c) {
                const int n = c * 64 + lane;
                const float d2 = sq3_rn(fr[n*3+0]-ax, fr[n*3+1]-ay, fr[n*3+2]-az);
                const bool hit = d2 < 0.25f;
                const unsigned long long mask = __ballot(hit);
                if (mask) {
                    if (cnt == 0) first = c * 64 + __builtin_ctzll(mask);
                    if (hit) {
                        const int pos = cnt + (int)__popcll(mask & ((1ull << lane) - 1ull));
                        if (pos < K_) sbidx[wa][pos] = (unsigned short)n;
                    }
                    cnt += (int)__popcll(mask);
                    if (cnt >= K_) break;
                }
            }
            if (lane < K_ && lane >= cnt) sbidx[wa][lane] = (unsigned short)(cnt ? first : 0);
        }

        // ---- phase A: gather + layer1 directly into B-fragments (hi/lo) ----
        bf16x8 bhi[2][2], blo[2][2];      // [nt][ks]
        {
            const int n0 = sbidx[wa][lm];
            const int n1 = sbidx[wa][16 + lm];
            const float* nx0 = xyzs + ((size_t)(b*8 + fi) * N_ + n0) * 3;
            const float* nx1 = xyzs + ((size_t)(b*8 + fi) * N_ + n1) * 3;
            const float* fp  = feats + (size_t)(b*8 + fi) * (3 * N_);
            const float s00 = nx0[0]-ax, s01 = nx0[1]-ay, s02 = nx0[2]-az;
            const float s10 = nx1[0]-ax, s11 = nx1[1]-ay, s12 = nx1[2]-az;
            const float f00 = fp[n0], f01 = fp[N_ + n0], f02 = fp[2*N_ + n0];
            const float f10 = fp[n1], f11 = fp[N_ + n1], f12 = fp[2*N_ + n1];
#pragma unroll
            for (int ks = 0; ks < 2; ++ks) {
#pragma unroll
                for (int jj = 0; jj < 8; ++jj) {
                    const int o = ks * 32 + lg * 8 + jj;
                    const float4 A  = *(const float4*)&w0s[o][0];
                    const float4 Bv = *(const float4*)&w0s[o][4];   // .z/.w unused
                    const float r0 = fmaxf(A.x*s00 + A.y*s01 + A.z*s02 +
                                           A.w*f00 + Bv.x*f01 + Bv.y*f02, 0.f);
                    const float r1 = fmaxf(A.x*s10 + A.y*s11 + A.z*s12 +
                                           A.w*f10 + Bv.x*f11 + Bv.y*f12, 0.f);
                    const unsigned short h0 = f2bf(r0);
                    const unsigned short h1 = f2bf(r1);
                    bhi[0][ks][jj] = (short)h0;
                    blo[0][ks][jj] = (short)f2bf(r0 - bf2f(h0));
                    bhi[1][ks][jj] = (short)h1;
                    blo[1][ks][jj] = (short)f2bf(r1 - bf2f(h1));
                }
            }
        }

        // ---- phase B: MFMA GEMM 128oc x 32q, split-bf16 (hh+hl+lh) ----
        {
            f32x4 acc[8][2];
#pragma unroll
            for (int mt = 0; mt < 8; ++mt) {
                acc[mt][0] = (f32x4){0.f, 0.f, 0.f, 0.f};
                acc[mt][1] = (f32x4){0.f, 0.f, 0.f, 0.f};
            }
#pragma unroll
            for (int mt = 0; mt < 8; ++mt) {
#pragma unroll
                for (int ks = 0; ks < 2; ++ks) {
                    const int oc = mt * 16 + lm;
                    const int kb = ks * 32 + lg * 8;
                    const int idx = oc * 64 + ((((kb >> 3) ^ (oc & 7))) << 3);
                    const bf16x8 ahi = *(const bf16x8*)&ws1s[0][idx];
                    const bf16x8 alo = *(const bf16x8*)&ws1s[1][idx];
#pragma unroll
                    for (int nt = 0; nt < 2; ++nt) {
                        acc[mt][nt] = __builtin_amdgcn_mfma_f32_16x16x32_bf16(
                            ahi, bhi[nt][ks], acc[mt][nt], 0, 0, 0);
                        acc[mt][nt] = __builtin_amdgcn_mfma_f32_16x16x32_bf16(
                            ahi, blo[nt][ks], acc[mt][nt], 0, 0, 0);
                        acc[mt][nt] = __builtin_amdgcn_mfma_f32_16x16x32_bf16(
                            alo, bhi[nt][ks], acc[mt][nt], 0, 0, 0);
                    }
                }
            }
            // maxpool over 32 q: across nt then across lm bits (1,2,4,8)
#pragma unroll
            for (int mt = 0; mt < 8; ++mt) {
                float mr0 = fmaxf(acc[mt][0][0], acc[mt][1][0]);
                float mr1 = fmaxf(acc[mt][0][1], acc[mt][1][1]);
                float mr2 = fmaxf(acc[mt][0][2], acc[mt][1][2]);
                float mr3 = fmaxf(acc[mt][0][3], acc[mt][1][3]);
#pragma unroll
                for (int off = 1; off < 16; off <<= 1) {
                    mr0 = fmaxf(mr0, __shfl_xor(mr0, off));
                    mr1 = fmaxf(mr1, __shfl_xor(mr1, off));
                    mr2 = fmaxf(mr2, __shfl_xor(mr2, off));
                    mr3 = fmaxf(mr3, __shfl_xor(mr3, off));
                }
                if (lm == 0)    // D row = lg*4 + r within tile mt
                    *(float4*)&hmaxs[wa][mt * 16 + lg * 4] =
                        make_float4(fmaxf(mr0, 0.f), fmaxf(mr1, 0.f),
                                    fmaxf(mr2, 0.f), fmaxf(mr3, 0.f));
            }
        }

        // ---- phase C: st += relu(Wt[j][lane*4+r] . hmax[wa]) ----
        {
            const float4* wr = (const float4*)(Wt + ((size_t)j << 15) + ((size_t)lane << 9));
            const float4* hm = (const float4*)&hmaxs[wa][0];
            float c0 = 0.f, c1 = 0.f, c2 = 0.f, c3 = 0.f;
#pragma unroll 4
            for (int k4 = 0; k4 < 32; ++k4) {
                const float4 h  = hm[k4];        // broadcast (same-wave data)
                const float4 w0 = wr[k4];
                const float4 w1 = wr[32 + k4];
                const float4 w2 = wr[64 + k4];
                const float4 w3 = wr[96 + k4];
                c0 += w0.x*h.x + w0.y*h.y + w0.z*h.z + w0.w*h.w;
                c1 += w1.x*h.x + w1.y*h.y + w1.z*h.z + w1.w*h.w;
                c2 += w2.x*h.x + w2.y*h.y + w2.z*h.z + w2.w*h.w;
                c3 += w3.x*h.x + w3.y*h.y + w3.z*h.z + w3.w*h.w;
            }
            st0 += fmaxf(c0, 0.f);
            st1 += fmaxf(c1, 0.f);
            st2 += fmaxf(c2, 0.f);
            st3 += fmaxf(c3, 0.f);
        }
    }

    // ---- coalesced output: transpose via stg (overlays ws1s) ----
    __syncthreads();                      // all waves done reading ws1s
    stg[(lane * 4 + 0) * 6 + wa] = st0;
    stg[(lane * 4 + 1) * 6 + wa] = st1;
    stg[(lane * 4 + 2) * 6 + wa] = st2;
    stg[(lane * 4 + 3) * 6 + wa] = st3;
    __syncthreads();
    {
        float4 o;
        o.x = stg[tid * 6 + 0];
        o.y = stg[tid * 6 + 1];
        o.z = stg[tid * 6 + 2];
        o.w = stg[tid * 6 + 3];
        *(float4*)(out_feat + ((size_t)bt * 256 + tid) * M_ + mb * 4) = o;
    }
}

// ---------------------------------------------------------------------------
extern "C" void kernel_launch(void* const* d_in, const int* in_sizes, int n_in,
                              void* d_out, int out_size, void* d_ws, size_t ws_size,
                              hipStream_t stream) {
    const float* xyzs  = (const float*)d_in[0];
    const float* feats = (const float*)d_in[1];
    const float* Ws0   = (const float*)d_in[2];
    const float* Ws1   = (const float*)d_in[3];
    const float* Wt    = (const float*)d_in[4];

    float* out_xyz  = (float*)d_out;
    float* out_feat = out_xyz + (size_t)B_ * 8 * M_ * 3;

    (void)d_ws; (void)ws_size;

    fps_kernel<<<B_ * 8, 512, 0, stream>>>(xyzs, out_xyz);
    mlp_kernel<<<B_ * 8 * (M_ / 4), 256, 0, stream>>>(xyzs, feats, Ws0, Ws1, Wt,
                                                      out_xyz, out_feat);
}

// Round 7
// 6885.139 us; speedup vs baseline: 1.3480x; 1.3480x over previous
//
#include <hip/hip_runtime.h>
#include <cstddef>

#define B_  4
#define N_  4096
#define M_  2048
#define K_  32      // NSAMPLE

typedef short bf16x8 __attribute__((ext_vector_type(8)));
typedef float f32x4  __attribute__((ext_vector_type(4)));

// IEEE mul/add without fma contraction: FPS argmax and ball-query d2<r^2 are
// DISCRETE selectors. This exact form PASSED rounds 2,3,6.
__device__ __forceinline__ float sq3_rn(float dx, float dy, float dz) {
    return __fadd_rn(__fadd_rn(__fmul_rn(dx, dx), __fmul_rn(dy, dy)), __fmul_rn(dz, dz));
}

// float -> bf16 (RNE) and back, bit-level
__device__ __forceinline__ unsigned short f2bf(float f) {
    unsigned u = __float_as_uint(f);
    return (unsigned short)((u + 0x7FFFu + ((u >> 16) & 1u)) >> 16);
}
__device__ __forceinline__ float bf2f(unsigned short h) {
    return __uint_as_float(((unsigned)h) << 16);
}

// ---------------------------------------------------------------------------
// FPS: unchanged from round 5/6 (measured ~960 us, matched prediction).
// ---------------------------------------------------------------------------
__global__ __launch_bounds__(512) void fps_kernel(
    const float* __restrict__ xyzs,   // [B,8,4096,3]
    float* __restrict__ out_xyz)      // [B,8,2048,3]
{
    const int blk = blockIdx.x;
    const int tid = threadIdx.x;
    const float* fr = xyzs + (size_t)blk * (N_ * 3);
    float* ox = out_xyz + (size_t)blk * (M_ * 3);

    __shared__ float sx[N_], sy[N_], sz[N_];
    __shared__ unsigned long long sred[2][8];

    float px[8], py[8], pz[8], dist[8];
    unsigned ids[8];
#pragma unroll
    for (int u = 0; u < 8; ++u) {
        const int p = u * 512 + tid;
        const float x = fr[p*3+0], y = fr[p*3+1], z = fr[p*3+2];
        px[u] = x; py[u] = y; pz[u] = z; dist[u] = 1e10f;
        ids[u] = ~(unsigned)p;
        sx[p] = x; sy[p] = y; sz[p] = z;
    }
    __syncthreads();

    const int lane = tid & 63, wave = tid >> 6;
    int last = 0;
    int widx[4];
#pragma unroll
    for (int s = 0; s < 4; ++s) {
        for (int ii = 0; ii < 512; ++ii) {
            if (ii == tid) widx[s] = last;   // output of iter s*512+ii = pre-update last
            const float lx = sx[last], ly = sy[last], lz = sz[last];

            unsigned long long best = 0ull;
#pragma unroll
            for (int u = 0; u < 8; ++u) {
                const float d = sq3_rn(px[u]-lx, py[u]-ly, pz[u]-lz);
                const float nd = fminf(dist[u], d);
                dist[u] = nd;
                const unsigned long long pk =
                    ((unsigned long long)__float_as_uint(nd) << 32) | ids[u];
                best = pk > best ? pk : best;
            }
#pragma unroll
            for (int off = 32; off; off >>= 1) {
                const unsigned long long o = __shfl_xor(best, off);
                best = o > best ? o : best;
            }
            if (lane == 0) sred[ii & 1][wave] = best;
            __syncthreads();
            const unsigned long long* sr = sred[ii & 1];
            unsigned long long b0 = sr[0] > sr[1] ? sr[0] : sr[1];
            unsigned long long b1 = sr[2] > sr[3] ? sr[2] : sr[3];
            unsigned long long b2 = sr[4] > sr[5] ? sr[4] : sr[5];
            unsigned long long b3 = sr[6] > sr[7] ? sr[6] : sr[7];
            b0 = b0 > b1 ? b0 : b1;
            b2 = b2 > b3 ? b2 : b3;
            b0 = b0 > b2 ? b0 : b2;
            last = (int)((~(unsigned)b0) & (N_ - 1));
        }
    }
#pragma unroll
    for (int s = 0; s < 4; ++s) {
        const int it = s * 512 + tid;
        const int w = widx[s];
        ox[it*3+0] = sx[w]; ox[it*3+1] = sy[w]; ox[it*3+2] = sz[w];
    }
}

// ---------------------------------------------------------------------------
// Fused per-wave pipeline (round-6 structure, register-pressure fixed):
//   - B-fragments: 8 NAMED bf16x8 vars (bh{nt}{ks}/bl{nt}{ks}), no arrays
//   - phase B: accumulators live only within one mt iteration (16 VGPRs,
//     4 independent chains), 4-term split (hh + hl + lh + ll)
//   - __launch_bounds__(256,2): the rounds-2/3 no-spill configuration
// ---------------------------------------------------------------------------
__global__ __launch_bounds__(256, 2) void mlp_kernel(
    const float* __restrict__ xyzs,      // [B,8,4096,3]
    const float* __restrict__ feats,     // [B,8,3,4096]
    const float* __restrict__ Ws0,       // [64,6]
    const float* __restrict__ Ws1,       // [128,64]
    const float* __restrict__ Wt,        // [3,256,128]
    const float* __restrict__ anchors,   // [B,8,2048,3]
    float* __restrict__ out_feat)        // [B,8,256,2048]
{
    const int blk = blockIdx.x;
    const int mb  = blk & 511;
    const int bt  = blk >> 9;
    const int b = bt >> 3, t = bt & 7;
    const int tid = threadIdx.x;
    const int lane = tid & 63, wa = tid >> 6;
    const int lm = lane & 15, lg = lane >> 4;

    // ws1s[part][idx]: idx(oc,k) = oc*64 + (((k>>3)^(oc&7))<<3) + (k&7)
    __shared__ unsigned short ws1s[2][128 * 64];   // 32 KB
    __shared__ float w0s[64][8];                   // 2 KB (cols 6,7 unused)
    __shared__ float hmaxs[4][128];                // 2 KB
    __shared__ float ancs[4][3];
    __shared__ unsigned short sbidx[4][32];
    float* stg = (float*)ws1s;                     // end-of-kernel overlay (6 KB)

    // ---- one-time staging ----
    for (int i = tid; i < 384; i += 256) w0s[i / 6][i % 6] = Ws0[i];
    {
        const float4* wp4 = (const float4*)Ws1;    // 2048 float4
#pragma unroll
        for (int u = 0; u < 8; ++u) {
            const int f4 = u * 256 + tid;
            const float4 v = wp4[f4];
            const int oc = f4 >> 4;
            const int k0 = (f4 & 15) * 4;
            const float vv[4] = {v.x, v.y, v.z, v.w};
#pragma unroll
            for (int c = 0; c < 4; ++c) {
                const int k = k0 + c;
                const int idx = oc * 64 + (((k >> 3) ^ (oc & 7)) << 3) + (k & 7);
                const unsigned short hi = f2bf(vv[c]);
                const unsigned short lo = f2bf(vv[c] - bf2f(hi));
                ws1s[0][idx] = hi;
                ws1s[1][idx] = lo;
            }
        }
    }
    if (tid < 12) ancs[tid / 3][tid % 3] =
        anchors[((size_t)bt * M_ + mb * 4 + tid / 3) * 3 + tid % 3];
    __syncthreads();

    const float ax = ancs[wa][0], ay = ancs[wa][1], az = ancs[wa][2];
    float st0 = 0.f, st1 = 0.f, st2 = 0.f, st3 = 0.f;   // oc = lane*4 + r

    for (int j = 0; j < 3; ++j) {
        int fi = t + j - 1; fi = fi < 0 ? 0 : (fi > 7 ? 7 : fi);
        const float* fr = xyzs + (size_t)(b * 8 + fi) * (N_ * 3);

        // ---- ball query (per wave; same-wave LDS readback, no barrier) ----
        {
            int cnt = 0, first = 0;
            for (int c = 0; c < 64; ++c) {
                const int n = c * 64 + lane;
                const float d2 = sq3_rn(fr[n*3+0]-ax, fr[n*3+1]-ay, fr[n*3+2]-az);
                const bool hit = d2 < 0.25f;
                const unsigned long long mask = __ballot(hit);
                if (mask) {
                    if (cnt == 0) first = c * 64 + __builtin_ctzll(mask);
                    if (hit) {
                        const int pos = cnt + (int)__popcll(mask & ((1ull << lane) - 1ull));
                        if (pos < K_) sbidx[wa][pos] = (unsigned short)n;
                    }
                    cnt += (int)__popcll(mask);
                    if (cnt >= K_) break;
                }
            }
            if (lane < K_ && lane >= cnt) sbidx[wa][lane] = (unsigned short)(cnt ? first : 0);
        }

        // ---- phase A: gather + layer1 into NAMED B-fragment registers ----
        // lane l holds q = nt*16 + lm, k = ks*32 + lg*8 + jj
        bf16x8 bh00, bh01, bh10, bh11, bl00, bl01, bl10, bl11;  // bh{nt}{ks}
        {
            const int n0 = sbidx[wa][lm];
            const int n1 = sbidx[wa][16 + lm];
            const float* nx0 = xyzs + ((size_t)(b*8 + fi) * N_ + n0) * 3;
            const float* nx1 = xyzs + ((size_t)(b*8 + fi) * N_ + n1) * 3;
            const float* fp  = feats + (size_t)(b*8 + fi) * (3 * N_);
            const float s00 = nx0[0]-ax, s01 = nx0[1]-ay, s02 = nx0[2]-az;
            const float s10 = nx1[0]-ax, s11 = nx1[1]-ay, s12 = nx1[2]-az;
            const float f00 = fp[n0], f01 = fp[N_ + n0], f02 = fp[2*N_ + n0];
            const float f10 = fp[n1], f11 = fp[N_ + n1], f12 = fp[2*N_ + n1];
#define LAYER1(KS, BH0v, BL0v, BH1v, BL1v)                                        \
            {                                                                     \
                _Pragma("unroll")                                                 \
                for (int jj = 0; jj < 8; ++jj) {                                  \
                    const int o = (KS) * 32 + lg * 8 + jj;                        \
                    const float4 Av = *(const float4*)&w0s[o][0];                 \
                    const float4 Bv = *(const float4*)&w0s[o][4];                 \
                    const float r0 = fmaxf(Av.x*s00 + Av.y*s01 + Av.z*s02 +       \
                                           Av.w*f00 + Bv.x*f01 + Bv.y*f02, 0.f);  \
                    const float r1 = fmaxf(Av.x*s10 + Av.y*s11 + Av.z*s12 +       \
                                           Av.w*f10 + Bv.x*f11 + Bv.y*f12, 0.f);  \
                    const unsigned short h0 = f2bf(r0), h1 = f2bf(r1);            \
                    BH0v[jj] = (short)h0;                                         \
                    BL0v[jj] = (short)f2bf(r0 - bf2f(h0));                        \
                    BH1v[jj] = (short)h1;                                         \
                    BL1v[jj] = (short)f2bf(r1 - bf2f(h1));                        \
                }                                                                 \
            }
            LAYER1(0, bh00, bl00, bh10, bl10)
            LAYER1(1, bh01, bl01, bh11, bl11)
#undef LAYER1
        }

        // ---- phase B: MFMA GEMM, accumulators transient per mt tile ----
#define MFMA(a, bb, c) __builtin_amdgcn_mfma_f32_16x16x32_bf16(a, bb, c, 0, 0, 0)
#pragma unroll
        for (int mt = 0; mt < 8; ++mt) {
            const int oc  = mt * 16 + lm;
            const int row = oc * 64;
            const int sw  = oc & 7;
            const bf16x8 ah0 = *(const bf16x8*)&ws1s[0][row + ((lg ^ sw) << 3)];
            const bf16x8 al0 = *(const bf16x8*)&ws1s[1][row + ((lg ^ sw) << 3)];
            const bf16x8 ah1 = *(const bf16x8*)&ws1s[0][row + (((4 + lg) ^ sw) << 3)];
            const bf16x8 al1 = *(const bf16x8*)&ws1s[1][row + (((4 + lg) ^ sw) << 3)];
            f32x4 cA0 = {0.f,0.f,0.f,0.f}, cB0 = {0.f,0.f,0.f,0.f};
            f32x4 cA1 = {0.f,0.f,0.f,0.f}, cB1 = {0.f,0.f,0.f,0.f};
            // nt = 0 (q 0..15): hh chain + (hl+lh+ll) chain, ks = 0 then 1
            cA0 = MFMA(ah0, bh00, cA0);
            cB0 = MFMA(ah0, bl00, cB0); cB0 = MFMA(al0, bh00, cB0); cB0 = MFMA(al0, bl00, cB0);
            cA0 = MFMA(ah1, bh01, cA0);
            cB0 = MFMA(ah1, bl01, cB0); cB0 = MFMA(al1, bh01, cB0); cB0 = MFMA(al1, bl01, cB0);
            // nt = 1 (q 16..31)
            cA1 = MFMA(ah0, bh10, cA1);
            cB1 = MFMA(ah0, bl10, cB1); cB1 = MFMA(al0, bh10, cB1); cB1 = MFMA(al0, bl10, cB1);
            cA1 = MFMA(ah1, bh11, cA1);
            cB1 = MFMA(ah1, bl11, cB1); cB1 = MFMA(al1, bh11, cB1); cB1 = MFMA(al1, bl11, cB1);
            // maxpool over 32 q: nt pair, then lm bits (1,2,4,8)
            float mr0 = fmaxf(cA0[0] + cB0[0], cA1[0] + cB1[0]);
            float mr1 = fmaxf(cA0[1] + cB0[1], cA1[1] + cB1[1]);
            float mr2 = fmaxf(cA0[2] + cB0[2], cA1[2] + cB1[2]);
            float mr3 = fmaxf(cA0[3] + cB0[3], cA1[3] + cB1[3]);
#pragma unroll
            for (int off = 1; off < 16; off <<= 1) {
                mr0 = fmaxf(mr0, __shfl_xor(mr0, off));
                mr1 = fmaxf(mr1, __shfl_xor(mr1, off));
                mr2 = fmaxf(mr2, __shfl_xor(mr2, off));
                mr3 = fmaxf(mr3, __shfl_xor(mr3, off));
            }
            if (lm == 0)    // D row = lg*4 + r within tile mt
                *(float4*)&hmaxs[wa][mt * 16 + lg * 4] =
                    make_float4(fmaxf(mr0, 0.f), fmaxf(mr1, 0.f),
                                fmaxf(mr2, 0.f), fmaxf(mr3, 0.f));
        }
#undef MFMA

        // ---- phase C: st += relu(Wt[j][lane*4+r] . hmax[wa]) ----
        {
            const float4* wr = (const float4*)(Wt + ((size_t)j << 15) + ((size_t)lane << 9));
            const float4* hm = (const float4*)&hmaxs[wa][0];
            float c0 = 0.f, c1 = 0.f, c2 = 0.f, c3 = 0.f;
#pragma unroll 4
            for (int k4 = 0; k4 < 32; ++k4) {
                const float4 h  = hm[k4];        // broadcast (same-wave data)
                const float4 w0 = wr[k4];
                const float4 w1 = wr[32 + k4];
                const float4 w2 = wr[64 + k4];
                const float4 w3 = wr[96 + k4];
                c0 += w0.x*h.x + w0.y*h.y + w0.z*h.z + w0.w*h.w;
                c1 += w1.x*h.x + w1.y*h.y + w1.z*h.z + w1.w*h.w;
                c2 += w2.x*h.x + w2.y*h.y + w2.z*h.z + w2.w*h.w;
                c3 += w3.x*h.x + w3.y*h.y + w3.z*h.z + w3.w*h.w;
            }
            st0 += fmaxf(c0, 0.f);
            st1 += fmaxf(c1, 0.f);
            st2 += fmaxf(c2, 0.f);
            st3 += fmaxf(c3, 0.f);
        }
    }

    // ---- coalesced output: transpose via stg (overlays ws1s) ----
    __syncthreads();                      // all waves done reading ws1s
    stg[(lane * 4 + 0) * 6 + wa] = st0;
    stg[(lane * 4 + 1) * 6 + wa] = st1;
    stg[(lane * 4 + 2) * 6 + wa] = st2;
    stg[(lane * 4 + 3) * 6 + wa] = st3;
    __syncthreads();
    {
        float4 o;
        o.x = stg[tid * 6 + 0];
        o.y = stg[tid * 6 + 1];
        o.z = stg[tid * 6 + 2];
        o.w = stg[tid * 6 + 3];
        *(float4*)(out_feat + ((size_t)bt * 256 + tid) * M_ + mb * 4) = o;
    }
}

// ---------------------------------------------------------------------------
extern "C" void kernel_launch(void* const* d_in, const int* in_sizes, int n_in,
                              void* d_out, int out_size, void* d_ws, size_t ws_size,
                              hipStream_t stream) {
    const float* xyzs  = (const float*)d_in[0];
    const float* feats = (const float*)d_in[1];
    const float* Ws0   = (const float*)d_in[2];
    const float* Ws1   = (const float*)d_in[3];
    const float* Wt    = (const float*)d_in[4];

    float* out_xyz  = (float*)d_out;
    float* out_feat = out_xyz + (size_t)B_ * 8 * M_ * 3;

    (void)d_ws; (void)ws_size;

    fps_kernel<<<B_ * 8, 512, 0, stream>>>(xyzs, out_xyz);
    mlp_kernel<<<B_ * 8 * (M_ / 4), 256, 0, stream>>>(xyzs, feats, Ws0, Ws1, Wt,
                                                      out_xyz, out_feat);
}

// Round 10
// 6002.915 us; speedup vs baseline: 1.5462x; 1.1470x over previous
//
#include <hip/hip_runtime.h>
#include <cstddef>

#define B_  4
#define N_  4096
#define M_  2048
#define K_  32      // NSAMPLE

typedef short bf16x8 __attribute__((ext_vector_type(8)));
typedef float f32x4  __attribute__((ext_vector_type(4)));

// IEEE mul/add without fma contraction: FPS argmax and ball-query d2<r^2 are
// DISCRETE selectors. This exact form PASSED rounds 2,3,6,7.
__device__ __forceinline__ float sq3_rn(float dx, float dy, float dz) {
    return __fadd_rn(__fadd_rn(__fmul_rn(dx, dx), __fmul_rn(dy, dy)), __fmul_rn(dz, dz));
}

// float -> bf16 (RNE) and back, bit-level
__device__ __forceinline__ unsigned short f2bf(float f) {
    unsigned u = __float_as_uint(f);
    return (unsigned short)((u + 0x7FFFu + ((u >> 16) & 1u)) >> 16);
}
__device__ __forceinline__ float bf2f(unsigned short h) {
    return __uint_as_float(((unsigned)h) << 16);
}

// ---------------------------------------------------------------------------
// FPS: unchanged since round 5 (measured ~960 us, matched prediction).
// ---------------------------------------------------------------------------
__global__ __launch_bounds__(512) void fps_kernel(
    const float* __restrict__ xyzs,   // [B,8,4096,3]
    float* __restrict__ out_xyz)      // [B,8,2048,3]
{
    const int blk = blockIdx.x;
    const int tid = threadIdx.x;
    const float* fr = xyzs + (size_t)blk * (N_ * 3);
    float* ox = out_xyz + (size_t)blk * (M_ * 3);

    __shared__ float sx[N_], sy[N_], sz[N_];
    __shared__ unsigned long long sred[2][8];

    float px[8], py[8], pz[8], dist[8];
    unsigned ids[8];
#pragma unroll
    for (int u = 0; u < 8; ++u) {
        const int p = u * 512 + tid;
        const float x = fr[p*3+0], y = fr[p*3+1], z = fr[p*3+2];
        px[u] = x; py[u] = y; pz[u] = z; dist[u] = 1e10f;
        ids[u] = ~(unsigned)p;
        sx[p] = x; sy[p] = y; sz[p] = z;
    }
    __syncthreads();

    const int lane = tid & 63, wave = tid >> 6;
    int last = 0;
    int widx[4];
#pragma unroll
    for (int s = 0; s < 4; ++s) {
        for (int ii = 0; ii < 512; ++ii) {
            if (ii == tid) widx[s] = last;   // output of iter s*512+ii = pre-update last
            const float lx = sx[last], ly = sy[last], lz = sz[last];

            unsigned long long best = 0ull;
#pragma unroll
            for (int u = 0; u < 8; ++u) {
                const float d = sq3_rn(px[u]-lx, py[u]-ly, pz[u]-lz);
                const float nd = fminf(dist[u], d);
                dist[u] = nd;
                const unsigned long long pk =
                    ((unsigned long long)__float_as_uint(nd) << 32) | ids[u];
                best = pk > best ? pk : best;
            }
#pragma unroll
            for (int off = 32; off; off >>= 1) {
                const unsigned long long o = __shfl_xor(best, off);
                best = o > best ? o : best;
            }
            if (lane == 0) sred[ii & 1][wave] = best;
            __syncthreads();
            const unsigned long long* sr = sred[ii & 1];
            unsigned long long b0 = sr[0] > sr[1] ? sr[0] : sr[1];
            unsigned long long b1 = sr[2] > sr[3] ? sr[2] : sr[3];
            unsigned long long b2 = sr[4] > sr[5] ? sr[4] : sr[5];
            unsigned long long b3 = sr[6] > sr[7] ? sr[6] : sr[7];
            b0 = b0 > b1 ? b0 : b1;
            b2 = b2 > b3 ? b2 : b3;
            b0 = b0 > b2 ? b0 : b2;
            last = (int)((~(unsigned)b0) & (N_ - 1));
        }
    }
#pragma unroll
    for (int s = 0; s < 4; ++s) {
        const int it = s * 512 + tid;
        const int w = widx[s];
        ox[it*3+0] = sx[w]; ox[it*3+1] = sy[w]; ox[it*3+2] = sz[w];
    }
}

// ---------------------------------------------------------------------------
// Fused per-wave pipeline, spill-free restructure (round 7 -> 8):
//   - h1 staged through LDS (bf16 hi/lo, XOR-swizzled 16B slots), so phase-A
//     transients die before phase-B fragments go live (peak VGPR ~85)
//   - mt loop NOT unrolled (unroll 1): A-fragments transient per iteration,
//     no cross-tile ds_read hoisting (the round-6/7 spill cause)
//   - still ZERO barriers in the j-loop: all h1s/sbidx/hmaxs traffic is
//     same-wave (LDS pipe is program-ordered per wave); sched_barrier(0)
//     between phase A writes and phase B reads as reorder insurance
// ---------------------------------------------------------------------------
__global__ __launch_bounds__(256, 2) void mlp_kernel(
    const float* __restrict__ xyzs,      // [B,8,4096,3]
    const float* __restrict__ feats,     // [B,8,3,4096]
    const float* __restrict__ Ws0,       // [64,6]
    const float* __restrict__ Ws1,       // [128,64]
    const float* __restrict__ Wt,        // [3,256,128]
    const float* __restrict__ anchors,   // [B,8,2048,3]
    float* __restrict__ out_feat)        // [B,8,256,2048]
{
    const int blk = blockIdx.x;
    const int mb  = blk & 511;
    const int bt  = blk >> 9;
    const int b = bt >> 3, t = bt & 7;
    const int tid = threadIdx.x;
    const int lane = tid & 63, wa = tid >> 6;
    const int lm = lane & 15, lg = lane >> 4;

    // ws1s[part][idx]: idx(oc,k) = oc*64 + (((k>>3)^(oc&7))<<3) + (k&7)
    __shared__ unsigned short ws1s[2][128 * 64];   // 32 KB
    // h1s flat ushort: [(wa*2+part)*32 + q][64 k], 16B slot (k>>3) stored at
    // slot ((k>>3)^(q&7)) -> both write and read phases hit all 32 banks
    __shared__ unsigned short h1s[4 * 2 * 32 * 64];  // 32 KB
    __shared__ float w0s[64][8];                   // 2 KB (cols 6,7 unused)
    __shared__ float hmaxs[4][128];                // 2 KB
    __shared__ float ancs[4][3];
    __shared__ unsigned short sbidx[4][32];
    float* stg = (float*)ws1s;                     // end-of-kernel overlay (6 KB)

    // ---- one-time staging ----
    for (int i = tid; i < 384; i += 256) w0s[i / 6][i % 6] = Ws0[i];
    {
        const float4* wp4 = (const float4*)Ws1;    // 2048 float4
#pragma unroll
        for (int u = 0; u < 8; ++u) {
            const int f4 = u * 256 + tid;
            const float4 v = wp4[f4];
            const int oc = f4 >> 4;
            const int k0 = (f4 & 15) * 4;
            const float vv[4] = {v.x, v.y, v.z, v.w};
#pragma unroll
            for (int c = 0; c < 4; ++c) {
                const int k = k0 + c;
                const int idx = oc * 64 + (((k >> 3) ^ (oc & 7)) << 3) + (k & 7);
                const unsigned short hi = f2bf(vv[c]);
                const unsigned short lo = f2bf(vv[c] - bf2f(hi));
                ws1s[0][idx] = hi;
                ws1s[1][idx] = lo;
            }
        }
    }
    if (tid < 12) ancs[tid / 3][tid % 3] =
        anchors[((size_t)bt * M_ + mb * 4 + tid / 3) * 3 + tid % 3];
    __syncthreads();

    const float ax = ancs[wa][0], ay = ancs[wa][1], az = ancs[wa][2];
    const int q  = lane & 31;            // phase-A q owned by this lane
    const int kh = lane >> 5;            // phase-A k-half (0..1)
    float st0 = 0.f, st1 = 0.f, st2 = 0.f, st3 = 0.f;   // oc = lane*4 + r

    for (int j = 0; j < 3; ++j) {
        int fi = t + j - 1; fi = fi < 0 ? 0 : (fi > 7 ? 7 : fi);
        const float* fr = xyzs + (size_t)(b * 8 + fi) * (N_ * 3);

        // ---- ball query (per wave; same-wave LDS readback, no barrier) ----
        {
            int cnt = 0, first = 0;
            for (int c = 0; c < 64; ++c) {
                const int n = c * 64 + lane;
                const float d2 = sq3_rn(fr[n*3+0]-ax, fr[n*3+1]-ay, fr[n*3+2]-az);
                const bool hit = d2 < 0.25f;
                const unsigned long long mask = __ballot(hit);
                if (mask) {
                    if (cnt == 0) first = c * 64 + __builtin_ctzll(mask);
                    if (hit) {
                        const int pos = cnt + (int)__popcll(mask & ((1ull << lane) - 1ull));
                        if (pos < K_) sbidx[wa][pos] = (unsigned short)n;
                    }
                    cnt += (int)__popcll(mask);
                    if (cnt >= K_) break;
                }
            }
            if (lane < K_ && lane >= cnt) sbidx[wa][lane] = (unsigned short)(cnt ? first : 0);
        }

        // ---- phase A: gather + layer1 -> h1s (LDS, bf16 hi/lo) ----
        // lane (q, kh) computes k = kh*32 .. +31 for its q, in chunks of 8
        {
            const int n = sbidx[wa][q];
            const float* nx = xyzs + ((size_t)(b*8 + fi) * N_ + n) * 3;
            const float* fp = feats + (size_t)(b*8 + fi) * (3 * N_);
            const float s0 = nx[0]-ax, s1 = nx[1]-ay, s2 = nx[2]-az;
            const float f0 = fp[n], f1 = fp[N_ + n], f2 = fp[2*N_ + n];
            const int rbase0 = ((wa * 2 + 0) * 32 + q) << 6;
            const int rbase1 = ((wa * 2 + 1) * 32 + q) << 6;
#pragma unroll
            for (int c = 0; c < 4; ++c) {
                const int k0 = kh * 32 + c * 8;
                bf16x8 vh, vl;
#pragma unroll
                for (int jj = 0; jj < 8; ++jj) {
                    const int o = k0 + jj;
                    const float4 Av = *(const float4*)&w0s[o][0];
                    const float4 Bv = *(const float4*)&w0s[o][4];  // .z/.w unused
                    const float r = fmaxf(Av.x*s0 + Av.y*s1 + Av.z*s2 +
                                          Av.w*f0 + Bv.x*f1 + Bv.y*f2, 0.f);
                    const unsigned short h = f2bf(r);
                    vh[jj] = (short)h;
                    vl[jj] = (short)f2bf(r - bf2f(h));
                }
                const int slot = ((k0 >> 3) ^ (q & 7)) << 3;
                *(bf16x8*)&h1s[rbase0 + slot] = vh;
                *(bf16x8*)&h1s[rbase1 + slot] = vl;
            }
        }
        __builtin_amdgcn_sched_barrier(0);   // keep B-frag reads after A writes

        // ---- load B-fragments from h1s (8 named bf16x8, 32 VGPRs) ----
        // lane l: q' = nt*16+lm, k0 = ks*32+lg*8, slot = (ks*4+lg)^(q'&7)
        bf16x8 bh00, bh01, bh10, bh11, bl00, bl01, bl10, bl11;  // bh{nt}{ks}
        {
#define BLOAD(NT, KS, BH, BL)                                                  \
            {                                                                  \
                const int qq  = (NT) * 16 + lm;                                \
                const int sl  = (((KS) * 4 + lg) ^ (qq & 7)) << 3;             \
                BH = *(const bf16x8*)&h1s[(((wa*2 + 0) * 32 + qq) << 6) + sl]; \
                BL = *(const bf16x8*)&h1s[(((wa*2 + 1) * 32 + qq) << 6) + sl]; \
            }
            BLOAD(0, 0, bh00, bl00)
            BLOAD(0, 1, bh01, bl01)
            BLOAD(1, 0, bh10, bl10)
            BLOAD(1, 1, bh11, bl11)
#undef BLOAD
        }

        // ---- phase B: MFMA GEMM, one mt tile at a time (NOT unrolled) ----
#define MFMA(a, bb, c) __builtin_amdgcn_mfma_f32_16x16x32_bf16(a, bb, c, 0, 0, 0)
#pragma unroll 1
        for (int mt = 0; mt < 8; ++mt) {
            const int oc  = mt * 16 + lm;
            const int row = oc * 64;
            const int sw  = oc & 7;
            const bf16x8 ah0 = *(const bf16x8*)&ws1s[0][row + ((lg ^ sw) << 3)];
            const bf16x8 al0 = *(const bf16x8*)&ws1s[1][row + ((lg ^ sw) << 3)];
            const bf16x8 ah1 = *(const bf16x8*)&ws1s[0][row + (((4 + lg) ^ sw) << 3)];
            const bf16x8 al1 = *(const bf16x8*)&ws1s[1][row + (((4 + lg) ^ sw) << 3)];
            f32x4 cA0 = {0.f,0.f,0.f,0.f}, cB0 = {0.f,0.f,0.f,0.f};
            f32x4 cA1 = {0.f,0.f,0.f,0.f}, cB1 = {0.f,0.f,0.f,0.f};
            // nt = 0 (q 0..15): hh chain + (hl+lh+ll) chain, ks = 0 then 1
            cA0 = MFMA(ah0, bh00, cA0);
            cB0 = MFMA(ah0, bl00, cB0); cB0 = MFMA(al0, bh00, cB0); cB0 = MFMA(al0, bl00, cB0);
            cA0 = MFMA(ah1, bh01, cA0);
            cB0 = MFMA(ah1, bl01, cB0); cB0 = MFMA(al1, bh01, cB0); cB0 = MFMA(al1, bl01, cB0);
            // nt = 1 (q 16..31)
            cA1 = MFMA(ah0, bh10, cA1);
            cB1 = MFMA(ah0, bl10, cB1); cB1 = MFMA(al0, bh10, cB1); cB1 = MFMA(al0, bl10, cB1);
            cA1 = MFMA(ah1, bh11, cA1);
            cB1 = MFMA(ah1, bl11, cB1); cB1 = MFMA(al1, bh11, cB1); cB1 = MFMA(al1, bl11, cB1);
            // maxpool over 32 q: nt pair, then lm bits (1,2,4,8)
            float mr0 = fmaxf(cA0[0] + cB0[0], cA1[0] + cB1[0]);
            float mr1 = fmaxf(cA0[1] + cB0[1], cA1[1] + cB1[1]);
            float mr2 = fmaxf(cA0[2] + cB0[2], cA1[2] + cB1[2]);
            float mr3 = fmaxf(cA0[3] + cB0[3], cA1[3] + cB1[3]);
#pragma unroll
            for (int off = 1; off < 16; off <<= 1) {
                mr0 = fmaxf(mr0, __shfl_xor(mr0, off));
                mr1 = fmaxf(mr1, __shfl_xor(mr1, off));
                mr2 = fmaxf(mr2, __shfl_xor(mr2, off));
                mr3 = fmaxf(mr3, __shfl_xor(mr3, off));
            }
            if (lm == 0)    // D row = lg*4 + r within tile mt
                *(float4*)&hmaxs[wa][mt * 16 + lg * 4] =
                    make_float4(fmaxf(mr0, 0.f), fmaxf(mr1, 0.f),
                                fmaxf(mr2, 0.f), fmaxf(mr3, 0.f));
        }
#undef MFMA

        // ---- phase C: st += relu(Wt[j][lane*4+r] . hmax[wa]) ----
        {
            const float4* wr = (const float4*)(Wt + ((size_t)j << 15) + ((size_t)lane << 9));
            const float4* hm = (const float4*)&hmaxs[wa][0];
            float c0 = 0.f, c1 = 0.f, c2 = 0.f, c3 = 0.f;
#pragma unroll 4
            for (int k4 = 0; k4 < 32; ++k4) {
                const float4 h  = hm[k4];        // broadcast (same-wave data)
                const float4 w0 = wr[k4];
                const float4 w1 = wr[32 + k4];
                const float4 w2 = wr[64 + k4];
                const float4 w3 = wr[96 + k4];
                c0 += w0.x*h.x + w0.y*h.y + w0.z*h.z + w0.w*h.w;
                c1 += w1.x*h.x + w1.y*h.y + w1.z*h.z + w1.w*h.w;
                c2 += w2.x*h.x + w2.y*h.y + w2.z*h.z + w2.w*h.w;
                c3 += w3.x*h.x + w3.y*h.y + w3.z*h.z + w3.w*h.w;
            }
            st0 += fmaxf(c0, 0.f);
            st1 += fmaxf(c1, 0.f);
            st2 += fmaxf(c2, 0.f);
            st3 += fmaxf(c3, 0.f);
        }
    }

    // ---- coalesced output: transpose via stg (overlays ws1s) ----
    __syncthreads();                      // all waves done reading ws1s
    stg[(lane * 4 + 0) * 6 + wa] = st0;
    stg[(lane * 4 + 1) * 6 + wa] = st1;
    stg[(lane * 4 + 2) * 6 + wa] = st2;
    stg[(lane * 4 + 3) * 6 + wa] = st3;
    __syncthreads();
    {
        float4 o;
        o.x = stg[tid * 6 + 0];
        o.y = stg[tid * 6 + 1];
        o.z = stg[tid * 6 + 2];
        o.w = stg[tid * 6 + 3];
        *(float4*)(out_feat + ((size_t)bt * 256 + tid) * M_ + mb * 4) = o;
    }
}

// ---------------------------------------------------------------------------
extern "C" void kernel_launch(void* const* d_in, const int* in_sizes, int n_in,
                              void* d_out, int out_size, void* d_ws, size_t ws_size,
                              hipStream_t stream) {
    const float* xyzs  = (const float*)d_in[0];
    const float* feats = (const float*)d_in[1];
    const float* Ws0   = (const float*)d_in[2];
    const float* Ws1   = (const float*)d_in[3];
    const float* Wt    = (const float*)d_in[4];

    float* out_xyz  = (float*)d_out;
    float* out_feat = out_xyz + (size_t)B_ * 8 * M_ * 3;

    (void)d_ws; (void)ws_size;

    fps_kernel<<<B_ * 8, 512, 0, stream>>>(xyzs, out_xyz);
    mlp_kernel<<<B_ * 8 * (M_ / 4), 256, 0, stream>>>(xyzs, feats, Ws0, Ws1, Wt,
                                                      out_xyz, out_feat);
}